// Round 5
// baseline (297.558 us; speedup 1.0000x reference)
//
#include <hip/hip_runtime.h>

#define NN 50000
#define CAP 32          // per-node bin capacity; overflow handled correctly
#define OVF_CAP 4096
#define SHARD_W 64      // R16: 64-node shards; one bin_pass block OWNS a shard
#define NSH 782         // ceil(50000/64)
#define NPB 512         // partition blocks per relation

__device__ __forceinline__ unsigned short f2bf(float f) {
    unsigned u = __float_as_uint(f);
    u += 0x7fffu + ((u >> 16) & 1u);           // round-to-nearest-even
    return (unsigned short)(u >> 16);
}
__device__ __forceinline__ float bf2f(unsigned short u) {
    return __uint_as_float(((unsigned)u) << 16);
}

// Fused init: zero ovf_cnt AND convert x -> bf16. (deg fully written by
// bin_pass; hist/pbase/sbase fully written by their producers — no pre-zero.)
__global__ __launch_bounds__(256) void init_fuse(
    const float* __restrict__ in, unsigned short* __restrict__ out, int n4,
    int* __restrict__ zbuf, int nint)
{
    int stride = gridDim.x * blockDim.x;
    int id0 = blockIdx.x * blockDim.x + threadIdx.x;
    for (int i = id0; i < n4; i += stride) {
        float4 v = ((const float4*)in)[i];
        ushort4 o;
        o.x = f2bf(v.x); o.y = f2bf(v.y); o.z = f2bf(v.z); o.w = f2bf(v.w);
        ((ushort4*)out)[i] = o;
    }
    for (int i = id0; i < nint; i += stride) zbuf[i] = 0;
}

// ---- R16: shard-partition binning ----
// R12-R15 lesson: the chunked counting sort pays EITHER 8x masked-scan read
// redundancy (shard-affinity layout) OR 16x partial-line write amplification
// (chunk-affinity swizzle) — ~63MB at 1.4TB/s, ~75us, either way. Root cause:
// slot determinism machinery. But aggregation is a MEAN — slot order is free.
// So: partition edges by 64-node shard (exactly sized via hist+scan), then one
// block owns ALL edges of its shard and assigns slots with LDS atomics alone.
// Every pass is full-lane streaming; no cnt/bases planes, no prefix chains.
//
// Block->slice permutation in hist/partition: pb = (local&7)*64 + (local>>3).
// Blocks resident on one XCD (bid%8 const) get CONTIGUOUS pb -> their rank
// islands are adjacent in each shard stream -> compact-array lines are filled
// within one XCD (no cross-XCD partial-line writebacks).

__global__ __launch_bounds__(256) void shard_hist(
    const int* __restrict__ ei0, int E0,
    const int* __restrict__ ei1, int E1,
    unsigned short* __restrict__ hist16)        // [2][NPB][NSH] (aliases aggb)
{
    __shared__ unsigned lh[NSH];
    int local = blockIdx.x; int rel = 0;
    if (local >= NPB) { local -= NPB; rel = 1; }
    int pb = (local & 7) * (NPB / 8) + (local >> 3);
    const int* ei = rel ? ei1 : ei0;
    int E         = rel ? E1  : E0;
    int ce = (E + NPB - 1) / NPB;
    int lo = pb * ce, hi = min(lo + ce, E);

    for (int i = threadIdx.x; i < NSH; i += 256) lh[i] = 0;
    __syncthreads();
    for (int t = lo + threadIdx.x; t < hi; t += 256)
        atomicAdd(&lh[ei[E + t] >> 6], 1u);
    __syncthreads();
    unsigned short* row = hist16 + (size_t)(rel * NPB + pb) * NSH;
    for (int i = threadIdx.x; i < NSH; i += 256)
        row[i] = (unsigned short)lh[i];
}

// Per-(rel,shard) totals: sum hist over blocks.
__global__ __launch_bounds__(256) void total_pass(
    const unsigned short* __restrict__ hist16, int* __restrict__ tot)
{
    int i = blockIdx.x * 256 + threadIdx.x;     // row = rel*NSH + s
    if (i >= 2 * NSH) return;
    int rel = i / NSH, s = i - rel * NSH;
    int t = 0;
    for (int b = 0; b < NPB; b++)
        t += hist16[(size_t)(rel * NPB + b) * NSH + s];
    tot[i] = t;
}

// Exclusive scan of 1564 totals -> shard bases (+ sentinel). One block.
__global__ __launch_bounds__(256) void scan_pass(
    const int* __restrict__ tot, int* __restrict__ sbase)
{
    __shared__ int ps[256];
    int t = threadIdx.x;
    int v[7];
    int s = 0;
    #pragma unroll
    for (int j = 0; j < 7; j++) {
        int i = t * 7 + j;
        v[j] = (i < 2 * NSH) ? tot[i] : 0;
        s += v[j];
    }
    ps[t] = s;
    __syncthreads();
    for (int off = 1; off < 256; off <<= 1) {
        int add = (t >= off) ? ps[t - off] : 0;
        __syncthreads();
        ps[t] += add;
        __syncthreads();
    }
    int run = (t == 0) ? 0 : ps[t - 1];
    #pragma unroll
    for (int j = 0; j < 7; j++) {
        int i = t * 7 + j;
        if (i < 2 * NSH) sbase[i] = run;
        run += v[j];
    }
    if (t == 255) sbase[2 * NSH] = run;
}

// Per-(block,shard) bases: shard base + running sum of prior blocks' counts.
__global__ __launch_bounds__(256) void blockbase_pass(
    const unsigned short* __restrict__ hist16, const int* __restrict__ sbase,
    unsigned* __restrict__ pbase)               // [2][NPB][NSH] (aliases aggb)
{
    int i = blockIdx.x * 256 + threadIdx.x;
    if (i >= 2 * NSH) return;
    int rel = i / NSH, s = i - rel * NSH;
    unsigned run = (unsigned)sbase[i];
    for (int b = 0; b < NPB; b++) {
        size_t idx = (size_t)(rel * NPB + b) * NSH + s;
        pbase[idx] = run;
        run += hist16[idx];
    }
}

// Scatter edges into shard-segregated compact array: entry = (dst<<16)|src
// (both < 50000 < 65536). Ranks via LDS atomics; ranges reserved exactly.
__global__ __launch_bounds__(256) void partition_pass(
    const int* __restrict__ ei0, int E0,
    const int* __restrict__ ei1, int E1,
    const unsigned* __restrict__ pbase,
    unsigned* __restrict__ compact)             // [E0+E1] u32 (aliases h1b)
{
    __shared__ unsigned lbase[NSH];
    __shared__ unsigned lrank[NSH];
    int local = blockIdx.x; int rel = 0;
    if (local >= NPB) { local -= NPB; rel = 1; }
    int pb = (local & 7) * (NPB / 8) + (local >> 3);
    const int* ei = rel ? ei1 : ei0;
    int E         = rel ? E1  : E0;
    int ce = (E + NPB - 1) / NPB;
    int lo = pb * ce, hi = min(lo + ce, E);

    const unsigned* prow = pbase + (size_t)(rel * NPB + pb) * NSH;
    for (int i = threadIdx.x; i < NSH; i += 256) {
        lbase[i] = prow[i];
        lrank[i] = 0;
    }
    __syncthreads();
    for (int t = lo + threadIdx.x; t < hi; t += 256) {
        int dst = ei[E + t];
        int src = ei[t];
        int s = dst >> 6;
        unsigned r = atomicAdd(&lrank[s], 1u);
        compact[lbase[s] + r] = ((unsigned)dst << 16) | (unsigned)src;
    }
}

// One block per (rel,shard): owns ALL the shard's edges -> free slot order.
// bins region per block = 64 tasks x 64B = 4KB aligned: perfect write locality.
__global__ __launch_bounds__(256) void bin_pass(
    const unsigned* __restrict__ compact, const int* __restrict__ sbase,
    unsigned short* __restrict__ bins, int* __restrict__ deg,
    int2* __restrict__ ovf, int* __restrict__ ovf_cnt)
{
    __shared__ unsigned lcnt[SHARD_W];
    int bid = blockIdx.x;                       // = rel*NSH + s
    int rel = bid / NSH;
    int s   = bid - rel * NSH;
    if (threadIdx.x < SHARD_W) lcnt[threadIdx.x] = 0;
    __syncthreads();
    int base = sbase[bid];
    int tot  = sbase[bid + 1] - base;
    int taskbase = rel * NN + s * SHARD_W;
    for (int j = threadIdx.x; j < tot; j += 256) {
        unsigned e = compact[base + j];
        int dst = (int)(e >> 16);
        int src = (int)(e & 0xffffu);
        int loc = dst & (SHARD_W - 1);
        unsigned r = atomicAdd(&lcnt[loc], 1u);
        int task = taskbase + loc;
        if (r < CAP) {
            bins[(size_t)task * CAP + r] = (unsigned short)src;
        } else {
            int o = atomicAdd(ovf_cnt, 1);
            if (o < OVF_CAP) ovf[o] = make_int2(task, src);
        }
    }
    __syncthreads();
    if (threadIdx.x < SHARD_W) {
        int node = s * SHARD_W + threadIdx.x;
        if (node < NN) deg[rel * NN + node] = (int)lcnt[threadIdx.x];
    }
}

// One (rel,node) task per wave; paired bf16 gathers; inline overflow pickup.
// mean written in bf16 (one uint per lane) — agg consumed once by the GEMM.
__global__ __launch_bounds__(256) void aggregate(
    const unsigned short* __restrict__ bins, const int* __restrict__ deg,
    const unsigned short* __restrict__ hb, unsigned short* __restrict__ agg,
    const int2* __restrict__ ovf, const int* __restrict__ ovf_cnt)
{
    int lane = threadIdx.x & 63;
    int half = lane >> 5;
    int p = lane & 31;                 // feature-pair index
    int wid = (blockIdx.x * blockDim.x + threadIdx.x) >> 6;
    int nwaves = (gridDim.x * blockDim.x) >> 6;
    const unsigned int* hb32 = (const unsigned int*)hb;
    unsigned int* agg32 = (unsigned int*)agg;

    for (int task = wid; task < 2 * NN; task += nwaves) {
        int d = deg[task];
        int m = min(d, CAP);
        int idx = 0;
        if (lane < m) idx = bins[(size_t)task * CAP + lane];
        float a00=0.f,a01=0.f, a10=0.f,a11=0.f, a20=0.f,a21=0.f, a30=0.f,a31=0.f;
        int F = m >> 1;                // complete pair-steps
        int q = 0;
        for (; q + 4 <= F; q += 4) {
            int s0 = __shfl(idx, 2*(q+0) + half);
            int s1 = __shfl(idx, 2*(q+1) + half);
            int s2 = __shfl(idx, 2*(q+2) + half);
            int s3 = __shfl(idx, 2*(q+3) + half);
            unsigned u0 = hb32[(size_t)s0 * 32 + p];
            unsigned u1 = hb32[(size_t)s1 * 32 + p];
            unsigned u2 = hb32[(size_t)s2 * 32 + p];
            unsigned u3 = hb32[(size_t)s3 * 32 + p];
            a00 += __uint_as_float(u0 << 16); a01 += __uint_as_float(u0 & 0xffff0000u);
            a10 += __uint_as_float(u1 << 16); a11 += __uint_as_float(u1 & 0xffff0000u);
            a20 += __uint_as_float(u2 << 16); a21 += __uint_as_float(u2 & 0xffff0000u);
            a30 += __uint_as_float(u3 << 16); a31 += __uint_as_float(u3 & 0xffff0000u);
        }
        for (; q < F; ++q) {
            int s = __shfl(idx, 2*q + half);
            unsigned u = hb32[(size_t)s * 32 + p];
            a00 += __uint_as_float(u << 16); a01 += __uint_as_float(u & 0xffff0000u);
        }
        if (m & 1) {
            int s = __shfl(idx, m - 1);
            if (half == 0) {
                unsigned u = hb32[(size_t)s * 32 + p];
                a00 += __uint_as_float(u << 16); a01 += __uint_as_float(u & 0xffff0000u);
            }
        }
        if (d > CAP) {                 // rare: pick up this task's overflow edges
            int cnt = min(*ovf_cnt, OVF_CAP);
            for (int e = 0; e < cnt; ++e) {
                int2 v = ovf[e];
                if (v.x == task && half == 0) {
                    unsigned u = hb32[(size_t)v.y * 32 + p];
                    a00 += __uint_as_float(u << 16); a01 += __uint_as_float(u & 0xffff0000u);
                }
            }
        }
        float s0 = (a00 + a10) + (a20 + a30);
        float s1 = (a01 + a11) + (a21 + a31);
        s0 += __shfl_xor(s0, 32);
        s1 += __shfl_xor(s1, 32);
        if (half == 0) {
            float inv = 1.0f / (float)max(d, 1);
            unsigned lo = (unsigned)f2bf(s0 * inv);
            unsigned hi = (unsigned)f2bf(s1 * inv);
            agg32[(size_t)task * 32 + p] = lo | (hi << 16);
        }
    }
}

// L0: h1b = bf16( relu(mean0@Wl0 + mean1@Wl1 + self@(Wr0+Wr1) + b) ).
#define RST 132
__global__ __launch_bounds__(256) void layer_gemm(
    const unsigned short* __restrict__ agg0, const unsigned short* __restrict__ agg1,
    const unsigned short* __restrict__ selfb,
    const float* __restrict__ Wl0, const float* __restrict__ Wl1,
    const float* __restrict__ Wr0, const float* __restrict__ Wr1,
    const float* __restrict__ b0, const float* __restrict__ b1,
    unsigned short* __restrict__ hb16)
{
    __shared__ float Wch[64 * 64];
    __shared__ float rowsT[64 * RST];
    __shared__ float bias[64];

    int tid = threadIdx.x;
    int base = blockIdx.x * 128;
    if (tid < 64) bias[tid] = b0[tid] + b1[tid];

    int j8 = (tid & 7) * 8;
    int n4 = (tid >> 3) * 4;

    float acc[4][8];
    #pragma unroll
    for (int i = 0; i < 4; i++)
        #pragma unroll
        for (int c = 0; c < 8; c++) acc[i][c] = 0.f;

    for (int chunk = 0; chunk < 3; chunk++) {
        const float* W = (chunk == 0) ? Wl0 : (chunk == 1) ? Wl1 : Wr0;
        const unsigned short* src = (chunk == 0) ? agg0 : (chunk == 1) ? agg1 : selfb;
        __syncthreads();
        #pragma unroll
        for (int r = 0; r < 4; r++) {
            int i = tid + 256 * r;
            float4 w = *(const float4*)&W[i * 4];
            if (chunk == 2) {
                float4 w2 = *(const float4*)&Wr1[i * 4];
                w.x += w2.x; w.y += w2.y; w.z += w2.z; w.w += w2.w;
            }
            *(float4*)&Wch[i * 4] = w;
        }
        #pragma unroll
        for (int r = 0; r < 8; r++) {
            int i = tid + 256 * r;
            int node = i >> 4;
            int k4 = (i & 15) * 4;
            int g = base + node;
            ushort4 u = make_ushort4(0, 0, 0, 0);
            if (g < NN) u = *(const ushort4*)&src[(size_t)g * 64 + k4];
            rowsT[(k4 + 0) * RST + node] = bf2f(u.x);
            rowsT[(k4 + 1) * RST + node] = bf2f(u.y);
            rowsT[(k4 + 2) * RST + node] = bf2f(u.z);
            rowsT[(k4 + 3) * RST + node] = bf2f(u.w);
        }
        __syncthreads();
        #pragma unroll 4
        for (int k = 0; k < 64; k++) {
            float4 wa = *(const float4*)&Wch[k * 64 + j8];
            float4 wb = *(const float4*)&Wch[k * 64 + j8 + 4];
            float4 rv = *(const float4*)&rowsT[k * RST + n4];
            float w[8] = {wa.x, wa.y, wa.z, wa.w, wb.x, wb.y, wb.z, wb.w};
            float rr[4] = {rv.x, rv.y, rv.z, rv.w};
            #pragma unroll
            for (int i = 0; i < 4; i++)
                #pragma unroll
                for (int c = 0; c < 8; c++)
                    acc[i][c] = fmaf(rr[i], w[c], acc[i][c]);
        }
    }

    #pragma unroll
    for (int i = 0; i < 4; i++) {
        int g = base + n4 + i;
        if (g < NN) {
            ushort4 p0, p1;
            p0.x = f2bf(fmaxf(acc[i][0] + bias[j8 + 0], 0.f));
            p0.y = f2bf(fmaxf(acc[i][1] + bias[j8 + 1], 0.f));
            p0.z = f2bf(fmaxf(acc[i][2] + bias[j8 + 2], 0.f));
            p0.w = f2bf(fmaxf(acc[i][3] + bias[j8 + 3], 0.f));
            p1.x = f2bf(fmaxf(acc[i][4] + bias[j8 + 4], 0.f));
            p1.y = f2bf(fmaxf(acc[i][5] + bias[j8 + 5], 0.f));
            p1.z = f2bf(fmaxf(acc[i][6] + bias[j8 + 6], 0.f));
            p1.w = f2bf(fmaxf(acc[i][7] + bias[j8 + 7], 0.f));
            *(ushort4*)&hb16[(size_t)g * 64 + j8]     = p0;
            *(ushort4*)&hb16[(size_t)g * 64 + j8 + 4] = p1;
        }
    }
}

// L1 + final fused: h2 tile in LDS, then out = h2 @ linW + linb.
__global__ __launch_bounds__(256) void layer_gemm_final(
    const unsigned short* __restrict__ agg0, const unsigned short* __restrict__ agg1,
    const unsigned short* __restrict__ selfb,
    const float* __restrict__ Wl0, const float* __restrict__ Wl1,
    const float* __restrict__ Wr0, const float* __restrict__ Wr1,
    const float* __restrict__ b0, const float* __restrict__ b1,
    const float* __restrict__ linW, const float* __restrict__ linb,
    float* __restrict__ out)
{
    __shared__ float Wch[64 * 64];
    __shared__ float rowsT[64 * RST];
    __shared__ float bias[64];

    int tid = threadIdx.x;
    int base = blockIdx.x * 128;
    if (tid < 64) bias[tid] = b0[tid] + b1[tid];

    int j8 = (tid & 7) * 8;
    int n4 = (tid >> 3) * 4;

    float acc[4][8];
    #pragma unroll
    for (int i = 0; i < 4; i++)
        #pragma unroll
        for (int c = 0; c < 8; c++) acc[i][c] = 0.f;

    for (int chunk = 0; chunk < 3; chunk++) {
        const float* W = (chunk == 0) ? Wl0 : (chunk == 1) ? Wl1 : Wr0;
        const unsigned short* src = (chunk == 0) ? agg0 : (chunk == 1) ? agg1 : selfb;
        __syncthreads();
        #pragma unroll
        for (int r = 0; r < 4; r++) {
            int i = tid + 256 * r;
            float4 w = *(const float4*)&W[i * 4];
            if (chunk == 2) {
                float4 w2 = *(const float4*)&Wr1[i * 4];
                w.x += w2.x; w.y += w2.y; w.z += w2.z; w.w += w2.w;
            }
            *(float4*)&Wch[i * 4] = w;
        }
        #pragma unroll
        for (int r = 0; r < 8; r++) {
            int i = tid + 256 * r;
            int node = i >> 4;
            int k4 = (i & 15) * 4;
            int g = base + node;
            ushort4 u = make_ushort4(0, 0, 0, 0);
            if (g < NN) u = *(const ushort4*)&src[(size_t)g * 64 + k4];
            rowsT[(k4 + 0) * RST + node] = bf2f(u.x);
            rowsT[(k4 + 1) * RST + node] = bf2f(u.y);
            rowsT[(k4 + 2) * RST + node] = bf2f(u.z);
            rowsT[(k4 + 3) * RST + node] = bf2f(u.w);
        }
        __syncthreads();
        #pragma unroll 4
        for (int k = 0; k < 64; k++) {
            float4 wa = *(const float4*)&Wch[k * 64 + j8];
            float4 wb = *(const float4*)&Wch[k * 64 + j8 + 4];
            float4 rv = *(const float4*)&rowsT[k * RST + n4];
            float w[8] = {wa.x, wa.y, wa.z, wa.w, wb.x, wb.y, wb.z, wb.w};
            float rr[4] = {rv.x, rv.y, rv.z, rv.w};
            #pragma unroll
            for (int i = 0; i < 4; i++)
                #pragma unroll
                for (int c = 0; c < 8; c++)
                    acc[i][c] = fmaf(rr[i], w[c], acc[i][c]);
        }
    }

    // relu epilogue into registers
    float o[4][8];
    #pragma unroll
    for (int i = 0; i < 4; i++)
        #pragma unroll
        for (int c = 0; c < 8; c++)
            o[i][c] = fmaxf(acc[i][c] + bias[j8 + c], 0.f);

    __syncthreads();   // everyone done reading Wch/rowsT/bias

    // restage: Wch <- linW (64x32), bias <- linb, rowsT <- h2 tile transposed
    #pragma unroll
    for (int r = 0; r < 2; r++) {
        int i = tid + 256 * r;   // 512 float4 = 2048 floats
        *(float4*)&Wch[i * 4] = *(const float4*)&linW[i * 4];
    }
    if (tid < 32) bias[tid] = linb[tid];
    #pragma unroll
    for (int i = 0; i < 4; i++)
        #pragma unroll
        for (int c = 0; c < 8; c++)
            rowsT[(j8 + c) * RST + (n4 + i)] = o[i][c];
    __syncthreads();

    // mini-GEMM: out[128 x 32] = h2_tile @ linW + linb
    int j4 = (tid & 7) * 4;
    float acc2[4][4];
    #pragma unroll
    for (int i = 0; i < 4; i++)
        #pragma unroll
        for (int c = 0; c < 4; c++) acc2[i][c] = 0.f;
    #pragma unroll 4
    for (int k = 0; k < 64; k++) {
        float4 w = *(const float4*)&Wch[k * 32 + j4];
        float4 rv = *(const float4*)&rowsT[k * RST + n4];
        float wr[4] = {w.x, w.y, w.z, w.w};
        float rr[4] = {rv.x, rv.y, rv.z, rv.w};
        #pragma unroll
        for (int i = 0; i < 4; i++)
            #pragma unroll
            for (int c = 0; c < 4; c++)
                acc2[i][c] = fmaf(rr[i], wr[c], acc2[i][c]);
    }
    #pragma unroll
    for (int i = 0; i < 4; i++) {
        int g = base + n4 + i;
        if (g < NN) {
            float4 ov;
            ov.x = acc2[i][0] + bias[j4 + 0];
            ov.y = acc2[i][1] + bias[j4 + 1];
            ov.z = acc2[i][2] + bias[j4 + 2];
            ov.w = acc2[i][3] + bias[j4 + 3];
            *(float4*)&out[(size_t)g * 32 + j4] = ov;
        }
    }
}

extern "C" void kernel_launch(void* const* d_in, const int* in_sizes, int n_in,
                              void* d_out, int out_size, void* d_ws, size_t ws_size,
                              hipStream_t stream)
{
    const float* x    = (const float*)d_in[0];
    const int*   ei0  = (const int*)d_in[1];
    const int*   ei1  = (const int*)d_in[2];
    const float* Wl   = (const float*)d_in[3];   // [2,2,64,64]
    const float* Wr   = (const float*)d_in[4];   // [2,2,64,64]
    const float* bl   = (const float*)d_in[5];   // [2,2,64]
    const float* linW = (const float*)d_in[6];   // [64,32]
    const float* linb = (const float*)d_in[7];   // [32]
    float* out = (float*)d_out;

    int E0 = in_sizes[1] / 2;
    int E1 = in_sizes[2] / 2;

    // Workspace (unchanged footprint ~32.4MB); binning scratch aliases dead
    // regions:
    // [bins 6.4 | h1b 6.4 | aggb 12.8 | xb 6.4 | deg 0.4 | ovf]
    //   compact (6.4MB u32[E0+E1])      aliases h1b   (dead until layer_gemm)
    //   hist16  (1.6MB)                 aliases aggb+0    (dead until aggregate)
    //   pbase   (3.2MB)                 aliases aggb+1.6M
    //   tot/sbase (~13KB)               aliases aggb+4.8M
    unsigned short* bins = (unsigned short*)d_ws;
    unsigned short* h1b  = bins + (size_t)2 * NN * CAP;
    unsigned short* aggb = h1b + (size_t)NN * 64;
    unsigned short* agg0 = aggb;
    unsigned short* agg1 = aggb + (size_t)NN * 64;
    unsigned short* xb   = aggb + (size_t)2 * NN * 64;
    int*  deg     = (int*)(xb + (size_t)NN * 64);
    int*  ovf_cnt = deg + 2 * NN;
    int2* ovf     = (int2*)(ovf_cnt + 8);

    unsigned*       compact = (unsigned*)h1b;
    unsigned short* hist16  = aggb;
    unsigned*       pbase   = (unsigned*)(aggb + (size_t)2 * NPB * NSH);
    int*            tot     = (int*)(aggb + (size_t)2 * NPB * NSH * 3);
    int*            sbase   = tot + 2 * NSH;

    dim3 blk(256);
    int ggrid = (NN + 127) / 128;   // 391
    int rows_grid = (2 * NSH + 255) / 256;  // 7

    init_fuse<<<1024, blk, 0, stream>>>(x, xb, NN * 16, ovf_cnt, 8);

    // ---- shard-partition binning (R16) ----
    shard_hist<<<2 * NPB, blk, 0, stream>>>(ei0, E0, ei1, E1, hist16);
    total_pass<<<rows_grid, blk, 0, stream>>>(hist16, tot);
    scan_pass<<<1, blk, 0, stream>>>(tot, sbase);
    blockbase_pass<<<rows_grid, blk, 0, stream>>>(hist16, sbase, pbase);
    partition_pass<<<2 * NPB, blk, 0, stream>>>(ei0, E0, ei1, E1, pbase, compact);
    bin_pass<<<2 * NSH, blk, 0, stream>>>(compact, sbase, bins, deg, ovf, ovf_cnt);

    // ---- Layer 0 (gather + self from xb; h1b bf16 out) ----
    aggregate<<<4096, blk, 0, stream>>>(bins, deg, xb, aggb, ovf, ovf_cnt);
    layer_gemm<<<ggrid, blk, 0, stream>>>(agg0, agg1, xb,
        Wl + 0, Wl + 4096, Wr + 0, Wr + 4096, bl + 0, bl + 64, h1b);

    // ---- Layer 1 + final projection fused (h2 never materialized) ----
    aggregate<<<4096, blk, 0, stream>>>(bins, deg, h1b, aggb, ovf, ovf_cnt);
    layer_gemm_final<<<ggrid, blk, 0, stream>>>(agg0, agg1, h1b,
        Wl + 8192, Wl + 12288, Wr + 8192, Wr + 12288, bl + 128, bl + 192,
        linW, linb, out);
}

// Round 6
// 245.241 us; speedup vs baseline: 1.2133x; 1.2133x over previous
//
#include <hip/hip_runtime.h>

#define NN 50000
#define CAP 32          // per-node bin capacity; overflow handled correctly
#define OVF_CAP 4096
#define SHARD_W 64      // 64-node shards; one bin_pass block OWNS a shard
#define NSH 782         // ceil(50000/64)
#define NPB 512         // partition blocks per relation

__device__ __forceinline__ unsigned short f2bf(float f) {
    unsigned u = __float_as_uint(f);
    u += 0x7fffu + ((u >> 16) & 1u);           // round-to-nearest-even
    return (unsigned short)(u >> 16);
}
__device__ __forceinline__ float bf2f(unsigned short u) {
    return __uint_as_float(((unsigned)u) << 16);
}

// Fused init: zero ovf_cnt AND convert x -> bf16.
__global__ __launch_bounds__(256) void init_fuse(
    const float* __restrict__ in, unsigned short* __restrict__ out, int n4,
    int* __restrict__ zbuf, int nint)
{
    int stride = gridDim.x * blockDim.x;
    int id0 = blockIdx.x * blockDim.x + threadIdx.x;
    for (int i = id0; i < n4; i += stride) {
        float4 v = ((const float4*)in)[i];
        ushort4 o;
        o.x = f2bf(v.x); o.y = f2bf(v.y); o.z = f2bf(v.z); o.w = f2bf(v.w);
        ((ushort4*)out)[i] = o;
    }
    for (int i = id0; i < nint; i += stride) zbuf[i] = 0;
}

// ---- R17: shard-partition binning with TRANSPOSED hist/pbase ----
// R16 lesson: structure sound, but total/blockbase were 7-block serial loops
// (43.6us @ 0.23% occupancy each). R17: hist16[2][NSH][NPB] — each
// (rel,shard)'s 512 block-counts are one contiguous 1KB row, processed by ONE
// WAVE (coalesced uint4 loads + shfl scan). shard_hist's column writes stay
// XCD-clean: pb permutation gives XCD g ownership of pb [64g,64g+64) => every
// 64B line (32 pb) written by exactly one XCD.

__global__ __launch_bounds__(256) void shard_hist(
    const int* __restrict__ ei0, int E0,
    const int* __restrict__ ei1, int E1,
    unsigned short* __restrict__ hist16)        // [2][NSH][NPB] (aliases aggb)
{
    __shared__ unsigned lh[NSH];
    int local = blockIdx.x; int rel = 0;
    if (local >= NPB) { local -= NPB; rel = 1; }
    int pb = (local & 7) * (NPB / 8) + (local >> 3);
    const int* ei = rel ? ei1 : ei0;
    int E         = rel ? E1  : E0;
    int ce = (E + NPB - 1) / NPB;
    int lo = pb * ce, hi = min(lo + ce, E);

    for (int i = threadIdx.x; i < NSH; i += 256) lh[i] = 0;
    __syncthreads();
    for (int t = lo + threadIdx.x; t < hi; t += 256)
        atomicAdd(&lh[ei[E + t] >> 6], 1u);
    __syncthreads();
    for (int i = threadIdx.x; i < NSH; i += 256)
        hist16[((size_t)rel * NSH + i) * NPB + pb] = (unsigned short)lh[i];
}

// One wave per (rel,shard): coalesced row reduce.
__global__ __launch_bounds__(256) void total_pass(
    const unsigned short* __restrict__ hist16, int* __restrict__ tot)
{
    int gw = (blockIdx.x * 256 + threadIdx.x) >> 6;
    int lane = threadIdx.x & 63;
    if (gw >= 2 * NSH) return;
    uint4 v = ((const uint4*)(hist16 + (size_t)gw * NPB))[lane];
    unsigned s = (v.x & 0xffffu) + (v.x >> 16) + (v.y & 0xffffu) + (v.y >> 16)
               + (v.z & 0xffffu) + (v.z >> 16) + (v.w & 0xffffu) + (v.w >> 16);
    for (int off = 32; off; off >>= 1) s += __shfl_down(s, off);
    if (lane == 0) tot[gw] = (int)s;
}

// Exclusive scan of 1564 totals -> shard bases (+ sentinel). One block.
__global__ __launch_bounds__(256) void scan_pass(
    const int* __restrict__ tot, int* __restrict__ sbase)
{
    __shared__ int ps[256];
    int t = threadIdx.x;
    int v[7];
    int s = 0;
    #pragma unroll
    for (int j = 0; j < 7; j++) {
        int i = t * 7 + j;
        v[j] = (i < 2 * NSH) ? tot[i] : 0;
        s += v[j];
    }
    ps[t] = s;
    __syncthreads();
    for (int off = 1; off < 256; off <<= 1) {
        int add = (t >= off) ? ps[t - off] : 0;
        __syncthreads();
        ps[t] += add;
        __syncthreads();
    }
    int run = (t == 0) ? 0 : ps[t - 1];
    #pragma unroll
    for (int j = 0; j < 7; j++) {
        int i = t * 7 + j;
        if (i < 2 * NSH) sbase[i] = run;
        run += v[j];
    }
    if (t == 255) sbase[2 * NSH] = run;
}

// One wave per (rel,shard): lane-local prefix + shfl_up wave scan.
__global__ __launch_bounds__(256) void blockbase_pass(
    const unsigned short* __restrict__ hist16, const int* __restrict__ sbase,
    unsigned* __restrict__ pbase)               // [2][NSH][NPB] (aliases aggb)
{
    int gw = (blockIdx.x * 256 + threadIdx.x) >> 6;
    int lane = threadIdx.x & 63;
    if (gw >= 2 * NSH) return;
    uint4 v = ((const uint4*)(hist16 + (size_t)gw * NPB))[lane];
    unsigned c[8] = {v.x & 0xffffu, v.x >> 16, v.y & 0xffffu, v.y >> 16,
                     v.z & 0xffffu, v.z >> 16, v.w & 0xffffu, v.w >> 16};
    unsigned lsum = 0;
    #pragma unroll
    for (int j = 0; j < 8; j++) lsum += c[j];
    unsigned incl = lsum;
    for (int off = 1; off < 64; off <<= 1) {
        unsigned n = __shfl_up(incl, off);
        if (lane >= off) incl += n;
    }
    unsigned run = (unsigned)sbase[gw] + incl - lsum;
    unsigned* prow = pbase + (size_t)gw * NPB + lane * 8;
    #pragma unroll
    for (int j = 0; j < 8; j++) { prow[j] = run; run += c[j]; }
}

// Scatter edges into shard-segregated compact array: entry = (dst<<16)|src.
__global__ __launch_bounds__(256) void partition_pass(
    const int* __restrict__ ei0, int E0,
    const int* __restrict__ ei1, int E1,
    const unsigned* __restrict__ pbase,
    unsigned* __restrict__ compact)             // [E0+E1] u32 (aliases h1b)
{
    __shared__ unsigned lbase[NSH];
    __shared__ unsigned lrank[NSH];
    int local = blockIdx.x; int rel = 0;
    if (local >= NPB) { local -= NPB; rel = 1; }
    int pb = (local & 7) * (NPB / 8) + (local >> 3);
    const int* ei = rel ? ei1 : ei0;
    int E         = rel ? E1  : E0;
    int ce = (E + NPB - 1) / NPB;
    int lo = pb * ce, hi = min(lo + ce, E);

    for (int i = threadIdx.x; i < NSH; i += 256) {
        lbase[i] = pbase[((size_t)rel * NSH + i) * NPB + pb];
        lrank[i] = 0;
    }
    __syncthreads();
    for (int t = lo + threadIdx.x; t < hi; t += 256) {
        int dst = ei[E + t];
        int src = ei[t];
        int s = dst >> 6;
        unsigned r = atomicAdd(&lrank[s], 1u);
        compact[lbase[s] + r] = ((unsigned)dst << 16) | (unsigned)src;
    }
}

// One block per (rel,shard): owns ALL the shard's edges -> free slot order.
__global__ __launch_bounds__(256) void bin_pass(
    const unsigned* __restrict__ compact, const int* __restrict__ sbase,
    unsigned short* __restrict__ bins, int* __restrict__ deg,
    int2* __restrict__ ovf, int* __restrict__ ovf_cnt)
{
    __shared__ unsigned lcnt[SHARD_W];
    int bid = blockIdx.x;                       // = rel*NSH + s
    int rel = bid / NSH;
    int s   = bid - rel * NSH;
    if (threadIdx.x < SHARD_W) lcnt[threadIdx.x] = 0;
    __syncthreads();
    int base = sbase[bid];
    int tot  = sbase[bid + 1] - base;
    int taskbase = rel * NN + s * SHARD_W;
    for (int j = threadIdx.x; j < tot; j += 256) {
        unsigned e = compact[base + j];
        int dst = (int)(e >> 16);
        int src = (int)(e & 0xffffu);
        int loc = dst & (SHARD_W - 1);
        unsigned r = atomicAdd(&lcnt[loc], 1u);
        int task = taskbase + loc;
        if (r < CAP) {
            bins[(size_t)task * CAP + r] = (unsigned short)src;
        } else {
            int o = atomicAdd(ovf_cnt, 1);
            if (o < OVF_CAP) ovf[o] = make_int2(task, src);
        }
    }
    __syncthreads();
    if (threadIdx.x < SHARD_W) {
        int node = s * SHARD_W + threadIdx.x;
        if (node < NN) deg[rel * NN + node] = (int)lcnt[threadIdx.x];
    }
}

// One (rel,node) task per wave; paired bf16 gathers; inline overflow pickup.
__global__ __launch_bounds__(256) void aggregate(
    const unsigned short* __restrict__ bins, const int* __restrict__ deg,
    const unsigned short* __restrict__ hb, unsigned short* __restrict__ agg,
    const int2* __restrict__ ovf, const int* __restrict__ ovf_cnt)
{
    int lane = threadIdx.x & 63;
    int half = lane >> 5;
    int p = lane & 31;                 // feature-pair index
    int wid = (blockIdx.x * blockDim.x + threadIdx.x) >> 6;
    int nwaves = (gridDim.x * blockDim.x) >> 6;
    const unsigned int* hb32 = (const unsigned int*)hb;
    unsigned int* agg32 = (unsigned int*)agg;

    for (int task = wid; task < 2 * NN; task += nwaves) {
        int d = deg[task];
        int m = min(d, CAP);
        int idx = 0;
        if (lane < m) idx = bins[(size_t)task * CAP + lane];
        float a00=0.f,a01=0.f, a10=0.f,a11=0.f, a20=0.f,a21=0.f, a30=0.f,a31=0.f;
        int F = m >> 1;                // complete pair-steps
        int q = 0;
        for (; q + 4 <= F; q += 4) {
            int s0 = __shfl(idx, 2*(q+0) + half);
            int s1 = __shfl(idx, 2*(q+1) + half);
            int s2 = __shfl(idx, 2*(q+2) + half);
            int s3 = __shfl(idx, 2*(q+3) + half);
            unsigned u0 = hb32[(size_t)s0 * 32 + p];
            unsigned u1 = hb32[(size_t)s1 * 32 + p];
            unsigned u2 = hb32[(size_t)s2 * 32 + p];
            unsigned u3 = hb32[(size_t)s3 * 32 + p];
            a00 += __uint_as_float(u0 << 16); a01 += __uint_as_float(u0 & 0xffff0000u);
            a10 += __uint_as_float(u1 << 16); a11 += __uint_as_float(u1 & 0xffff0000u);
            a20 += __uint_as_float(u2 << 16); a21 += __uint_as_float(u2 & 0xffff0000u);
            a30 += __uint_as_float(u3 << 16); a31 += __uint_as_float(u3 & 0xffff0000u);
        }
        for (; q < F; ++q) {
            int s = __shfl(idx, 2*q + half);
            unsigned u = hb32[(size_t)s * 32 + p];
            a00 += __uint_as_float(u << 16); a01 += __uint_as_float(u & 0xffff0000u);
        }
        if (m & 1) {
            int s = __shfl(idx, m - 1);
            if (half == 0) {
                unsigned u = hb32[(size_t)s * 32 + p];
                a00 += __uint_as_float(u << 16); a01 += __uint_as_float(u & 0xffff0000u);
            }
        }
        if (d > CAP) {                 // rare: pick up this task's overflow edges
            int cnt = min(*ovf_cnt, OVF_CAP);
            for (int e = 0; e < cnt; ++e) {
                int2 v = ovf[e];
                if (v.x == task && half == 0) {
                    unsigned u = hb32[(size_t)v.y * 32 + p];
                    a00 += __uint_as_float(u << 16); a01 += __uint_as_float(u & 0xffff0000u);
                }
            }
        }
        float s0 = (a00 + a10) + (a20 + a30);
        float s1 = (a01 + a11) + (a21 + a31);
        s0 += __shfl_xor(s0, 32);
        s1 += __shfl_xor(s1, 32);
        if (half == 0) {
            float inv = 1.0f / (float)max(d, 1);
            unsigned lo = (unsigned)f2bf(s0 * inv);
            unsigned hi = (unsigned)f2bf(s1 * inv);
            agg32[(size_t)task * 32 + p] = lo | (hi << 16);
        }
    }
}

// L0: h1b = bf16( relu(mean0@Wl0 + mean1@Wl1 + self@(Wr0+Wr1) + b) ).
#define RST 132
__global__ __launch_bounds__(256) void layer_gemm(
    const unsigned short* __restrict__ agg0, const unsigned short* __restrict__ agg1,
    const unsigned short* __restrict__ selfb,
    const float* __restrict__ Wl0, const float* __restrict__ Wl1,
    const float* __restrict__ Wr0, const float* __restrict__ Wr1,
    const float* __restrict__ b0, const float* __restrict__ b1,
    unsigned short* __restrict__ hb16)
{
    __shared__ float Wch[64 * 64];
    __shared__ float rowsT[64 * RST];
    __shared__ float bias[64];

    int tid = threadIdx.x;
    int base = blockIdx.x * 128;
    if (tid < 64) bias[tid] = b0[tid] + b1[tid];

    int j8 = (tid & 7) * 8;
    int n4 = (tid >> 3) * 4;

    float acc[4][8];
    #pragma unroll
    for (int i = 0; i < 4; i++)
        #pragma unroll
        for (int c = 0; c < 8; c++) acc[i][c] = 0.f;

    for (int chunk = 0; chunk < 3; chunk++) {
        const float* W = (chunk == 0) ? Wl0 : (chunk == 1) ? Wl1 : Wr0;
        const unsigned short* src = (chunk == 0) ? agg0 : (chunk == 1) ? agg1 : selfb;
        __syncthreads();
        #pragma unroll
        for (int r = 0; r < 4; r++) {
            int i = tid + 256 * r;
            float4 w = *(const float4*)&W[i * 4];
            if (chunk == 2) {
                float4 w2 = *(const float4*)&Wr1[i * 4];
                w.x += w2.x; w.y += w2.y; w.z += w2.z; w.w += w2.w;
            }
            *(float4*)&Wch[i * 4] = w;
        }
        #pragma unroll
        for (int r = 0; r < 8; r++) {
            int i = tid + 256 * r;
            int node = i >> 4;
            int k4 = (i & 15) * 4;
            int g = base + node;
            ushort4 u = make_ushort4(0, 0, 0, 0);
            if (g < NN) u = *(const ushort4*)&src[(size_t)g * 64 + k4];
            rowsT[(k4 + 0) * RST + node] = bf2f(u.x);
            rowsT[(k4 + 1) * RST + node] = bf2f(u.y);
            rowsT[(k4 + 2) * RST + node] = bf2f(u.z);
            rowsT[(k4 + 3) * RST + node] = bf2f(u.w);
        }
        __syncthreads();
        #pragma unroll 4
        for (int k = 0; k < 64; k++) {
            float4 wa = *(const float4*)&Wch[k * 64 + j8];
            float4 wb = *(const float4*)&Wch[k * 64 + j8 + 4];
            float4 rv = *(const float4*)&rowsT[k * RST + n4];
            float w[8] = {wa.x, wa.y, wa.z, wa.w, wb.x, wb.y, wb.z, wb.w};
            float rr[4] = {rv.x, rv.y, rv.z, rv.w};
            #pragma unroll
            for (int i = 0; i < 4; i++)
                #pragma unroll
                for (int c = 0; c < 8; c++)
                    acc[i][c] = fmaf(rr[i], w[c], acc[i][c]);
        }
    }

    #pragma unroll
    for (int i = 0; i < 4; i++) {
        int g = base + n4 + i;
        if (g < NN) {
            ushort4 p0, p1;
            p0.x = f2bf(fmaxf(acc[i][0] + bias[j8 + 0], 0.f));
            p0.y = f2bf(fmaxf(acc[i][1] + bias[j8 + 1], 0.f));
            p0.z = f2bf(fmaxf(acc[i][2] + bias[j8 + 2], 0.f));
            p0.w = f2bf(fmaxf(acc[i][3] + bias[j8 + 3], 0.f));
            p1.x = f2bf(fmaxf(acc[i][4] + bias[j8 + 4], 0.f));
            p1.y = f2bf(fmaxf(acc[i][5] + bias[j8 + 5], 0.f));
            p1.z = f2bf(fmaxf(acc[i][6] + bias[j8 + 6], 0.f));
            p1.w = f2bf(fmaxf(acc[i][7] + bias[j8 + 7], 0.f));
            *(ushort4*)&hb16[(size_t)g * 64 + j8]     = p0;
            *(ushort4*)&hb16[(size_t)g * 64 + j8 + 4] = p1;
        }
    }
}

// L1 + final fused: h2 tile in LDS, then out = h2 @ linW + linb.
__global__ __launch_bounds__(256) void layer_gemm_final(
    const unsigned short* __restrict__ agg0, const unsigned short* __restrict__ agg1,
    const unsigned short* __restrict__ selfb,
    const float* __restrict__ Wl0, const float* __restrict__ Wl1,
    const float* __restrict__ Wr0, const float* __restrict__ Wr1,
    const float* __restrict__ b0, const float* __restrict__ b1,
    const float* __restrict__ linW, const float* __restrict__ linb,
    float* __restrict__ out)
{
    __shared__ float Wch[64 * 64];
    __shared__ float rowsT[64 * RST];
    __shared__ float bias[64];

    int tid = threadIdx.x;
    int base = blockIdx.x * 128;
    if (tid < 64) bias[tid] = b0[tid] + b1[tid];

    int j8 = (tid & 7) * 8;
    int n4 = (tid >> 3) * 4;

    float acc[4][8];
    #pragma unroll
    for (int i = 0; i < 4; i++)
        #pragma unroll
        for (int c = 0; c < 8; c++) acc[i][c] = 0.f;

    for (int chunk = 0; chunk < 3; chunk++) {
        const float* W = (chunk == 0) ? Wl0 : (chunk == 1) ? Wl1 : Wr0;
        const unsigned short* src = (chunk == 0) ? agg0 : (chunk == 1) ? agg1 : selfb;
        __syncthreads();
        #pragma unroll
        for (int r = 0; r < 4; r++) {
            int i = tid + 256 * r;
            float4 w = *(const float4*)&W[i * 4];
            if (chunk == 2) {
                float4 w2 = *(const float4*)&Wr1[i * 4];
                w.x += w2.x; w.y += w2.y; w.z += w2.z; w.w += w2.w;
            }
            *(float4*)&Wch[i * 4] = w;
        }
        #pragma unroll
        for (int r = 0; r < 8; r++) {
            int i = tid + 256 * r;
            int node = i >> 4;
            int k4 = (i & 15) * 4;
            int g = base + node;
            ushort4 u = make_ushort4(0, 0, 0, 0);
            if (g < NN) u = *(const ushort4*)&src[(size_t)g * 64 + k4];
            rowsT[(k4 + 0) * RST + node] = bf2f(u.x);
            rowsT[(k4 + 1) * RST + node] = bf2f(u.y);
            rowsT[(k4 + 2) * RST + node] = bf2f(u.z);
            rowsT[(k4 + 3) * RST + node] = bf2f(u.w);
        }
        __syncthreads();
        #pragma unroll 4
        for (int k = 0; k < 64; k++) {
            float4 wa = *(const float4*)&Wch[k * 64 + j8];
            float4 wb = *(const float4*)&Wch[k * 64 + j8 + 4];
            float4 rv = *(const float4*)&rowsT[k * RST + n4];
            float w[8] = {wa.x, wa.y, wa.z, wa.w, wb.x, wb.y, wb.z, wb.w};
            float rr[4] = {rv.x, rv.y, rv.z, rv.w};
            #pragma unroll
            for (int i = 0; i < 4; i++)
                #pragma unroll
                for (int c = 0; c < 8; c++)
                    acc[i][c] = fmaf(rr[i], w[c], acc[i][c]);
        }
    }

    // relu epilogue into registers
    float o[4][8];
    #pragma unroll
    for (int i = 0; i < 4; i++)
        #pragma unroll
        for (int c = 0; c < 8; c++)
            o[i][c] = fmaxf(acc[i][c] + bias[j8 + c], 0.f);

    __syncthreads();   // everyone done reading Wch/rowsT/bias

    // restage: Wch <- linW (64x32), bias <- linb, rowsT <- h2 tile transposed
    #pragma unroll
    for (int r = 0; r < 2; r++) {
        int i = tid + 256 * r;   // 512 float4 = 2048 floats
        *(float4*)&Wch[i * 4] = *(const float4*)&linW[i * 4];
    }
    if (tid < 32) bias[tid] = linb[tid];
    #pragma unroll
    for (int i = 0; i < 4; i++)
        #pragma unroll
        for (int c = 0; c < 8; c++)
            rowsT[(j8 + c) * RST + (n4 + i)] = o[i][c];
    __syncthreads();

    // mini-GEMM: out[128 x 32] = h2_tile @ linW + linb
    int j4 = (tid & 7) * 4;
    float acc2[4][4];
    #pragma unroll
    for (int i = 0; i < 4; i++)
        #pragma unroll
        for (int c = 0; c < 4; c++) acc2[i][c] = 0.f;
    #pragma unroll 4
    for (int k = 0; k < 64; k++) {
        float4 w = *(const float4*)&Wch[k * 32 + j4];
        float4 rv = *(const float4*)&rowsT[k * RST + n4];
        float wr[4] = {w.x, w.y, w.z, w.w};
        float rr[4] = {rv.x, rv.y, rv.z, rv.w};
        #pragma unroll
        for (int i = 0; i < 4; i++)
            #pragma unroll
            for (int c = 0; c < 4; c++)
                acc2[i][c] = fmaf(rr[i], wr[c], acc2[i][c]);
    }
    #pragma unroll
    for (int i = 0; i < 4; i++) {
        int g = base + n4 + i;
        if (g < NN) {
            float4 ov;
            ov.x = acc2[i][0] + bias[j4 + 0];
            ov.y = acc2[i][1] + bias[j4 + 1];
            ov.z = acc2[i][2] + bias[j4 + 2];
            ov.w = acc2[i][3] + bias[j4 + 3];
            *(float4*)&out[(size_t)g * 32 + j4] = ov;
        }
    }
}

extern "C" void kernel_launch(void* const* d_in, const int* in_sizes, int n_in,
                              void* d_out, int out_size, void* d_ws, size_t ws_size,
                              hipStream_t stream)
{
    const float* x    = (const float*)d_in[0];
    const int*   ei0  = (const int*)d_in[1];
    const int*   ei1  = (const int*)d_in[2];
    const float* Wl   = (const float*)d_in[3];   // [2,2,64,64]
    const float* Wr   = (const float*)d_in[4];   // [2,2,64,64]
    const float* bl   = (const float*)d_in[5];   // [2,2,64]
    const float* linW = (const float*)d_in[6];   // [64,32]
    const float* linb = (const float*)d_in[7];   // [32]
    float* out = (float*)d_out;

    int E0 = in_sizes[1] / 2;
    int E1 = in_sizes[2] / 2;

    // Workspace (~32.4MB); binning scratch aliases dead regions:
    // [bins 6.4 | h1b 6.4 | aggb 12.8 | xb 6.4 | deg 0.4 | ovf]
    //   compact (6.4MB u32[E0+E1])  aliases h1b  (dead until layer_gemm)
    //   hist16  [2][NSH][NPB] 1.6MB aliases aggb+0
    //   pbase   [2][NSH][NPB] 3.2MB aliases aggb+1.6M
    //   tot/sbase (~13KB)           aliases aggb+4.8M
    unsigned short* bins = (unsigned short*)d_ws;
    unsigned short* h1b  = bins + (size_t)2 * NN * CAP;
    unsigned short* aggb = h1b + (size_t)NN * 64;
    unsigned short* agg0 = aggb;
    unsigned short* agg1 = aggb + (size_t)NN * 64;
    unsigned short* xb   = aggb + (size_t)2 * NN * 64;
    int*  deg     = (int*)(xb + (size_t)NN * 64);
    int*  ovf_cnt = deg + 2 * NN;
    int2* ovf     = (int2*)(ovf_cnt + 8);

    unsigned*       compact = (unsigned*)h1b;
    unsigned short* hist16  = aggb;
    unsigned*       pbase   = (unsigned*)(aggb + (size_t)2 * NSH * NPB);
    int*            tot     = (int*)(aggb + (size_t)2 * NSH * NPB * 3);
    int*            sbase   = tot + 2 * NSH;

    dim3 blk(256);
    int ggrid = (NN + 127) / 128;   // 391
    int wave_grid = (2 * NSH * 64 + 255) / 256;  // 391 blocks: 1 wave/(rel,shard)

    init_fuse<<<1024, blk, 0, stream>>>(x, xb, NN * 16, ovf_cnt, 8);

    // ---- shard-partition binning (R17: wave-parallel scans) ----
    shard_hist<<<2 * NPB, blk, 0, stream>>>(ei0, E0, ei1, E1, hist16);
    total_pass<<<wave_grid, blk, 0, stream>>>(hist16, tot);
    scan_pass<<<1, blk, 0, stream>>>(tot, sbase);
    blockbase_pass<<<wave_grid, blk, 0, stream>>>(hist16, sbase, pbase);
    partition_pass<<<2 * NPB, blk, 0, stream>>>(ei0, E0, ei1, E1, pbase, compact);
    bin_pass<<<2 * NSH, blk, 0, stream>>>(compact, sbase, bins, deg, ovf, ovf_cnt);

    // ---- Layer 0 (gather + self from xb; h1b bf16 out) ----
    aggregate<<<4096, blk, 0, stream>>>(bins, deg, xb, aggb, ovf, ovf_cnt);
    layer_gemm<<<ggrid, blk, 0, stream>>>(agg0, agg1, xb,
        Wl + 0, Wl + 4096, Wr + 0, Wr + 4096, bl + 0, bl + 64, h1b);

    // ---- Layer 1 + final projection fused (h2 never materialized) ----
    aggregate<<<4096, blk, 0, stream>>>(bins, deg, h1b, aggb, ovf, ovf_cnt);
    layer_gemm_final<<<ggrid, blk, 0, stream>>>(agg0, agg1, h1b,
        Wl + 8192, Wl + 12288, Wr + 8192, Wr + 12288, bl + 128, bl + 192,
        linW, linb, out);
}